// Round 13
// baseline (16.565 us; speedup 1.0000x reference)
//
#include <hip/hip_runtime.h>

#define MAXS 512
#define TBLK 1024                // 16 waves, 4/SIMD
#define NWAVE (TBLK / 64)
#define NR 6                     // float4 rounds per window
#define WIN (TBLK * 4 * NR)      // 24576 points: mean 612/octant, 4-sigma > 512

// One block per (batch, octant); zero cross-block communication (R3/R4/R7:
// any device-scope sync costs 50-150us on gfx950). R12 lesson: the dual-u64
// wave scan (6-step dependent shuffle chain on the LDS pipe, shared by all
// 16 waves) is the hottest serial leg. Replace it with per-round BALLOTS:
// rank = popc(ballot & lt_mask) per element slot — fully parallel, no scan.
// Single window leg, single barrier; residual loop (P ~ 2e-5) keeps exactness.
__global__ __launch_bounds__(TBLK) void octant_ballot_kernel(
    const float* __restrict__ pcs, int* __restrict__ out, int N) {
  const int blk = blockIdx.x;
  const int b = blk >> 3;
  const unsigned o = (unsigned)(blk & 7);
  const int tid = threadIdx.x, wid = tid >> 6, lane = tid & 63;
  const float* __restrict__ xp = pcs + (size_t)b * 3 * N;
  const float* __restrict__ yp = xp + N;
  const float* __restrict__ zp = yp + N;
  int* __restrict__ ob = out + ((size_t)(b * 8) + o) * MAXS;

  __shared__ unsigned long long sW[2][NWAVE][2];  // [leg parity][wave][A/B]

  const int nWin = (N + WIN - 1) / WIN;
  unsigned base = 0;  // block-uniform: my octant's filled count
  const unsigned long long ltm = (1ull << lane) - 1ull;  // lanes below me
  const bool tx = (o & 4u) != 0u, ty = (o & 2u) != 0u, tz = (o & 1u) != 0u;

  float4 ax[NR], ay[NR], az[NR];  // 18 float4 = 72 VGPRs of data

  #define LOADR(W, j)                                                 \
    do {                                                              \
      const int _g = (W) * WIN + (j) * (TBLK * 4) + tid * 4;          \
      if ((W) < nWin && _g + 4 <= N) {  /* N%4==0 */                  \
        ax[j] = *(const float4*)(xp + _g);                            \
        ay[j] = *(const float4*)(yp + _g);                            \
        az[j] = *(const float4*)(zp + _g);                            \
      } else {                                                        \
        ax[j] = make_float4(2.f, 2.f, 2.f, 2.f);  /* sentinel */      \
        ay[j] = ax[j]; az[j] = ax[j];                                 \
      }                                                               \
    } while (0)

  // Classify + ballot-rank + scatter; ONE barrier. sW parity (K&1) prevents
  // write-after-read races between consecutive legs (barrier in between).
  #define PROCESS(K)                                                          \
    do {                                                                      \
      unsigned mbits[NR], pre[NR];                                            \
      unsigned long long cpkA = 0ull, cpkB = 0ull; /* u16 wave totals */      \
      _Pragma("unroll")                                                       \
      for (int j = 0; j < NR; ++j) {                                          \
        float xv[4], yv[4], zv[4];                                            \
        xv[0] = ax[j].x; xv[1] = ax[j].y; xv[2] = ax[j].z; xv[3] = ax[j].w;   \
        yv[0] = ay[j].x; yv[1] = ay[j].y; yv[2] = ay[j].z; yv[3] = ay[j].w;   \
        zv[0] = az[j].x; zv[1] = az[j].y; zv[2] = az[j].z; zv[3] = az[j].w;   \
        unsigned m = 0;                                                       \
        _Pragma("unroll")                                                     \
        for (int e = 0; e < 4; ++e) {                                         \
          /* per-op IEEE f32: match numpy exactly at the r2~1 boundary */     \
          const float r2 = __fadd_rn(                                         \
              __fadd_rn(__fmul_rn(xv[e], xv[e]), __fmul_rn(yv[e], yv[e])),    \
              __fmul_rn(zv[e], zv[e]));                                       \
          const bool mem = (r2 <= 1.0f) && ((xv[e] >= 0.f) == tx) &&          \
                           ((yv[e] >= 0.f) == ty) && ((zv[e] >= 0.f) == tz);  \
          m |= mem ? (1u << e) : 0u;                                          \
        }                                                                     \
        mbits[j] = m;                                                         \
        const unsigned long long b0 = __ballot((m & 1u) != 0u);               \
        const unsigned long long b1 = __ballot((m & 2u) != 0u);               \
        const unsigned long long b2 = __ballot((m & 4u) != 0u);               \
        const unsigned long long b3 = __ballot((m & 8u) != 0u);               \
        pre[j] = (unsigned)(__popcll(b0 & ltm) + __popcll(b1 & ltm) +         \
                            __popcll(b2 & ltm) + __popcll(b3 & ltm));         \
        const unsigned long long wt =                                         \
            (unsigned long long)(__popcll(b0) + __popcll(b1) +                \
                                 __popcll(b2) + __popcll(b3));                \
        if (j < 3) cpkA += wt << (16 * j); else cpkB += wt << (16 * (j - 3)); \
      }                                                                       \
      if (lane == 0) {  /* wave totals are lane-uniform */                    \
        sW[(K) & 1][wid][0] = cpkA; sW[(K) & 1][wid][1] = cpkB;               \
      }                                                                       \
      __syncthreads(); /* the only barrier of the leg */                      \
      unsigned long long totA = 0ull, totB = 0ull;                            \
      unsigned long long preWA = 0ull, preWB = 0ull;                          \
      _Pragma("unroll")                                                       \
      for (int w = 0; w < NWAVE; ++w) {  /* fields <= 4096 < 65536 */         \
        const unsigned long long vA = sW[(K) & 1][w][0];                      \
        const unsigned long long vB = sW[(K) & 1][w][1];                      \
        totA += vA; totB += vB;                                               \
        preWA += (w < wid) ? vA : 0ull;                                       \
        preWB += (w < wid) ? vB : 0ull;                                       \
      }                                                                       \
      unsigned racc = 0;                                                      \
      _Pragma("unroll")                                                       \
      for (int j = 0; j < NR; ++j) {                                          \
        const int sh = 16 * ((j < 3) ? j : (j - 3));                          \
        const unsigned wpre =                                                 \
            (unsigned)((((j < 3) ? preWA : preWB) >> sh) & 0xffffull);        \
        const unsigned tot =                                                  \
            (unsigned)((((j < 3) ? totA : totB) >> sh) & 0xffffull);          \
        unsigned r = base + racc + wpre + pre[j];                             \
        const int g = (K) * WIN + j * (TBLK * 4) + tid * 4;                   \
        const unsigned m = mbits[j];                                          \
        _Pragma("unroll")                                                     \
        for (int e = 0; e < 4; ++e) {                                         \
          if (m & (1u << e)) {                                                \
            if (r < MAXS) ob[(int)r] = g + e;                                 \
            ++r;                                                              \
          }                                                                   \
        }                                                                     \
        racc += tot;                                                          \
      }                                                                       \
      base += racc; /* block-uniform */                                       \
    } while (0)

  // ---- issue the whole window's 18 loads immediately (full MLP) ----
  #pragma unroll
  for (int j = 0; j < NR; ++j) LOADR(0, j);
  PROCESS(0);

  // ---- residual windows (exactness path; P ~ 2e-5 of being taken) ----
  for (int k = 1; k < nWin && base < MAXS; ++k) {
    #pragma unroll
    for (int j = 0; j < NR; ++j) LOADR(k, j);
    PROCESS(k);
  }
  #undef PROCESS
  #undef LOADR

  // tail: unfilled slots get -1 (zero stores when base >= MAXS)
  for (int i = (int)base + tid; i < MAXS; i += TBLK) ob[i] = -1;
}

extern "C" void kernel_launch(void* const* d_in, const int* in_sizes, int n_in,
                              void* d_out, int out_size, void* d_ws, size_t ws_size,
                              hipStream_t stream) {
  const float* pcs = (const float*)d_in[0];
  int* out = (int*)d_out;
  const int B = out_size / (8 * MAXS);   // 16
  const int N = in_sizes[0] / (3 * B);   // 200000
  octant_ballot_kernel<<<B * 8, TBLK, 0, stream>>>(pcs, out, N);
}

// Round 14
// 13.589 us; speedup vs baseline: 1.2190x; 1.2190x over previous
//
#include <hip/hip_runtime.h>

#define MAXS 512
#define TBLK 1024                // 16 waves, 4/SIMD
#define NWAVE (TBLK / 64)
#define NR 6                     // float4 rounds per window
#define WIN (TBLK * 4 * NR)      // 24576 points: mean 612/octant, 4-sigma > 512

// One block per (batch, octant); zero cross-block communication (R3/R4/R7:
// any device-scope sync costs 50-150us on gfx950).
// R13 lesson: ballots regressed; R12 scan structure restored.
// NEW: (1) XCD swizzle — map all 8 octant-blocks of a batch to the SAME XCD
// (blockIdx%8 round-robin heuristic) so the 7 sibling re-reads of the shared
// 288KB window hit XCD-local L2 (~34TB/s) instead of L3; (2) wave scan packs
// all 6 round-counts in ONE u64 (10-bit fields, inclusive <= 256), halving
// the serial shuffle chain; unpack to u16 fields only for the 16-wave LDS
// combine (sums <= 4096 need 16 bits).
__global__ __launch_bounds__(TBLK) void octant_xcd_kernel(
    const float* __restrict__ pcs, int* __restrict__ out, int N) {
  // swizzle: xcd = blockIdx%8; batches b and b+8 share an XCD (16 blocks/XCD)
  const int i = blockIdx.x;
  const int xcd = i & 7, slot = i >> 3;          // slot in [0,16)
  const int b = xcd + ((slot & 1) << 3);         // b % 8 == xcd
  const unsigned o = (unsigned)(slot >> 1);      // octant 0..7
  const int tid = threadIdx.x, wid = tid >> 6, lane = tid & 63;
  const float* __restrict__ xp = pcs + (size_t)b * 3 * N;
  const float* __restrict__ yp = xp + N;
  const float* __restrict__ zp = yp + N;
  int* __restrict__ ob = out + ((size_t)(b * 8) + o) * MAXS;

  __shared__ unsigned long long sW[2][NWAVE][2];  // [leg parity][wave][A/B u16]

  const int nWin = (N + WIN - 1) / WIN;
  unsigned base = 0;  // block-uniform: my octant's filled count
  const bool tx = (o & 4u) != 0u, ty = (o & 2u) != 0u, tz = (o & 1u) != 0u;

  float4 ax[NR], ay[NR], az[NR];  // 18 float4 = 72 VGPRs of data

  #define LOADR(W, j)                                                 \
    do {                                                              \
      const int _g = (W) * WIN + (j) * (TBLK * 4) + tid * 4;          \
      if ((W) < nWin && _g + 4 <= N) {  /* N%4==0 */                  \
        ax[j] = *(const float4*)(xp + _g);                            \
        ay[j] = *(const float4*)(yp + _g);                            \
        az[j] = *(const float4*)(zp + _g);                            \
      } else {                                                        \
        ax[j] = make_float4(2.f, 2.f, 2.f, 2.f);  /* sentinel */      \
        ay[j] = ax[j]; az[j] = ax[j];                                 \
      }                                                               \
    } while (0)

  // Classify + rank + scatter the register-held window; ONE barrier.
  // sW parity (K&1) prevents write-after-read races across legs.
  #define PROCESS(K)                                                          \
    do {                                                                      \
      unsigned mbits[NR];                                                     \
      unsigned long long cpk = 0ull;  /* 6 x 10-bit per-round counts */       \
      _Pragma("unroll")                                                       \
      for (int j = 0; j < NR; ++j) {                                          \
        float xv[4], yv[4], zv[4];                                            \
        xv[0] = ax[j].x; xv[1] = ax[j].y; xv[2] = ax[j].z; xv[3] = ax[j].w;   \
        yv[0] = ay[j].x; yv[1] = ay[j].y; yv[2] = ay[j].z; yv[3] = ay[j].w;   \
        zv[0] = az[j].x; zv[1] = az[j].y; zv[2] = az[j].z; zv[3] = az[j].w;   \
        unsigned m = 0;                                                       \
        _Pragma("unroll")                                                     \
        for (int e = 0; e < 4; ++e) {                                         \
          /* per-op IEEE f32: match numpy exactly at the r2~1 boundary */     \
          const float r2 = __fadd_rn(                                         \
              __fadd_rn(__fmul_rn(xv[e], xv[e]), __fmul_rn(yv[e], yv[e])),    \
              __fmul_rn(zv[e], zv[e]));                                       \
          const bool mem = (r2 <= 1.0f) && ((xv[e] >= 0.f) == tx) &&          \
                           ((yv[e] >= 0.f) == ty) && ((zv[e] >= 0.f) == tz);  \
          m |= mem ? (1u << e) : 0u;                                          \
        }                                                                     \
        mbits[j] = m;                                                         \
        cpk += (unsigned long long)__popc(m) << (10 * j);                     \
      }                                                                       \
      unsigned long long inc = cpk;  /* single-u64 wave scan, 6 steps */      \
      _Pragma("unroll")                                                       \
      for (int d = 1; d < 64; d <<= 1) {                                      \
        const unsigned long long t = __shfl_up(inc, (unsigned)d, 64);         \
        if (lane >= d) inc += t;                                              \
      }                                                                       \
      const unsigned long long exc = inc - cpk;                               \
      if (lane == 63) {  /* unpack 10-bit -> u16 fields for 16-wave sums */   \
        unsigned long long iA = 0ull, iB = 0ull;                              \
        _Pragma("unroll")                                                     \
        for (int j = 0; j < 3; ++j) {                                         \
          iA += ((inc >> (10 * j)) & 0x3ffull) << (16 * j);                   \
          iB += ((inc >> (10 * (j + 3))) & 0x3ffull) << (16 * j);             \
        }                                                                     \
        sW[(K) & 1][wid][0] = iA; sW[(K) & 1][wid][1] = iB;                   \
      }                                                                       \
      __syncthreads();  /* the only barrier of the leg */                     \
      unsigned long long totA = 0ull, totB = 0ull;                            \
      unsigned long long preWA = 0ull, preWB = 0ull;                          \
      _Pragma("unroll")                                                       \
      for (int w = 0; w < NWAVE; ++w) {  /* fields <= 4096 < 65536 */         \
        const unsigned long long vA = sW[(K) & 1][w][0];                      \
        const unsigned long long vB = sW[(K) & 1][w][1];                      \
        totA += vA; totB += vB;                                               \
        preWA += (w < wid) ? vA : 0ull;                                       \
        preWB += (w < wid) ? vB : 0ull;                                       \
      }                                                                       \
      unsigned racc = 0;                                                      \
      _Pragma("unroll")                                                       \
      for (int j = 0; j < NR; ++j) {                                          \
        const int sh = 16 * ((j < 3) ? j : (j - 3));                          \
        const unsigned wpre =                                                 \
            (unsigned)((((j < 3) ? preWA : preWB) >> sh) & 0xffffull);        \
        const unsigned tot =                                                  \
            (unsigned)((((j < 3) ? totA : totB) >> sh) & 0xffffull);          \
        unsigned r = base + racc + wpre +                                     \
                     (unsigned)((exc >> (10 * j)) & 0x3ffull);                \
        const int g = (K) * WIN + j * (TBLK * 4) + tid * 4;                   \
        const unsigned m = mbits[j];                                          \
        _Pragma("unroll")                                                     \
        for (int e = 0; e < 4; ++e) {                                         \
          if (m & (1u << e)) {                                                \
            if (r < MAXS) ob[(int)r] = g + e;                                 \
            ++r;                                                              \
          }                                                                   \
        }                                                                     \
        racc += tot;                                                          \
      }                                                                       \
      base += racc;  /* block-uniform */                                      \
    } while (0)

  // ---- issue the whole window's 18 loads immediately (full MLP) ----
  #pragma unroll
  for (int j = 0; j < NR; ++j) LOADR(0, j);
  PROCESS(0);

  // ---- residual windows (exactness path; P ~ 2e-5 of being taken) ----
  for (int k = 1; k < nWin && base < MAXS; ++k) {
    #pragma unroll
    for (int j = 0; j < NR; ++j) LOADR(k, j);
    PROCESS(k);
  }
  #undef PROCESS
  #undef LOADR

  // tail: unfilled slots get -1 (zero stores when base >= MAXS)
  for (int i2 = (int)base + tid; i2 < MAXS; i2 += TBLK) ob[i2] = -1;
}

extern "C" void kernel_launch(void* const* d_in, const int* in_sizes, int n_in,
                              void* d_out, int out_size, void* d_ws, size_t ws_size,
                              hipStream_t stream) {
  const float* pcs = (const float*)d_in[0];
  int* out = (int*)d_out;
  const int B = out_size / (8 * MAXS);   // 16
  const int N = in_sizes[0] / (3 * B);   // 200000
  octant_xcd_kernel<<<B * 8, TBLK, 0, stream>>>(pcs, out, N);
}

// Round 15
// 13.518 us; speedup vs baseline: 1.2254x; 1.0052x over previous
//
#include <hip/hip_runtime.h>

#define MAXS 512
#define TBLK 1024                // 16 waves, 4/SIMD
#define NWAVE (TBLK / 64)
#define NR 6                     // float4 rounds per window
#define WIN (TBLK * 4 * NR)      // 24576 points: mean 611/octant, 4-sigma > 512

// One block per (batch, octant); zero cross-block communication (R3/R4/R7:
// any device-scope sync costs 50-150us on gfx950).
// Frozen from R14 (13.6us): XCD swizzle (8 octant-siblings share an XCD ->
// window re-reads hit XCD-local L2), single-u64 10-bit packed wave scan,
// one window leg, one barrier. NEW in R15: sparse ctz-walk scatter — wave
// runs only max-set-bits iterations per round (~1-2) instead of always 4,
// cutting ~70 VALU ops/thread from the scatter leg.
__global__ __launch_bounds__(TBLK) void octant_ctz_kernel(
    const float* __restrict__ pcs, int* __restrict__ out, int N) {
  // swizzle: xcd = blockIdx%8; batches b and b+8 share an XCD (16 blocks/XCD)
  const int i = blockIdx.x;
  const int xcd = i & 7, slot = i >> 3;          // slot in [0,16)
  const int b = xcd + ((slot & 1) << 3);         // b % 8 == xcd
  const unsigned o = (unsigned)(slot >> 1);      // octant 0..7
  const int tid = threadIdx.x, wid = tid >> 6, lane = tid & 63;
  const float* __restrict__ xp = pcs + (size_t)b * 3 * N;
  const float* __restrict__ yp = xp + N;
  const float* __restrict__ zp = yp + N;
  int* __restrict__ ob = out + ((size_t)(b * 8) + o) * MAXS;

  __shared__ unsigned long long sW[2][NWAVE][2];  // [leg parity][wave][A/B u16]

  const int nWin = (N + WIN - 1) / WIN;
  unsigned base = 0;  // block-uniform: my octant's filled count
  const bool tx = (o & 4u) != 0u, ty = (o & 2u) != 0u, tz = (o & 1u) != 0u;

  float4 ax[NR], ay[NR], az[NR];  // 18 float4 = 72 VGPRs of data

  #define LOADR(W, j)                                                 \
    do {                                                              \
      const int _g = (W) * WIN + (j) * (TBLK * 4) + tid * 4;          \
      if ((W) < nWin && _g + 4 <= N) {  /* N%4==0 */                  \
        ax[j] = *(const float4*)(xp + _g);                            \
        ay[j] = *(const float4*)(yp + _g);                            \
        az[j] = *(const float4*)(zp + _g);                            \
      } else {                                                        \
        ax[j] = make_float4(2.f, 2.f, 2.f, 2.f);  /* sentinel */      \
        ay[j] = ax[j]; az[j] = ax[j];                                 \
      }                                                               \
    } while (0)

  // Classify + rank + scatter the register-held window; ONE barrier.
  // sW parity (K&1) prevents write-after-read races across legs.
  #define PROCESS(K)                                                          \
    do {                                                                      \
      unsigned mbits[NR];                                                     \
      unsigned long long cpk = 0ull;  /* 6 x 10-bit per-round counts */       \
      _Pragma("unroll")                                                       \
      for (int j = 0; j < NR; ++j) {                                          \
        float xv[4], yv[4], zv[4];                                            \
        xv[0] = ax[j].x; xv[1] = ax[j].y; xv[2] = ax[j].z; xv[3] = ax[j].w;   \
        yv[0] = ay[j].x; yv[1] = ay[j].y; yv[2] = ay[j].z; yv[3] = ay[j].w;   \
        zv[0] = az[j].x; zv[1] = az[j].y; zv[2] = az[j].z; zv[3] = az[j].w;   \
        unsigned m = 0;                                                       \
        _Pragma("unroll")                                                     \
        for (int e = 0; e < 4; ++e) {                                         \
          /* per-op IEEE f32: match numpy exactly at the r2~1 boundary */     \
          const float r2 = __fadd_rn(                                         \
              __fadd_rn(__fmul_rn(xv[e], xv[e]), __fmul_rn(yv[e], yv[e])),    \
              __fmul_rn(zv[e], zv[e]));                                       \
          const bool mem = (r2 <= 1.0f) && ((xv[e] >= 0.f) == tx) &&          \
                           ((yv[e] >= 0.f) == ty) && ((zv[e] >= 0.f) == tz);  \
          m |= mem ? (1u << e) : 0u;                                          \
        }                                                                     \
        mbits[j] = m;                                                         \
        cpk += (unsigned long long)__popc(m) << (10 * j);                     \
      }                                                                       \
      unsigned long long inc = cpk;  /* single-u64 wave scan, 6 steps */      \
      _Pragma("unroll")                                                       \
      for (int d = 1; d < 64; d <<= 1) {                                      \
        const unsigned long long t = __shfl_up(inc, (unsigned)d, 64);         \
        if (lane >= d) inc += t;                                              \
      }                                                                       \
      const unsigned long long exc = inc - cpk;                               \
      if (lane == 63) {  /* unpack 10-bit -> u16 fields for 16-wave sums */   \
        unsigned long long iA = 0ull, iB = 0ull;                              \
        _Pragma("unroll")                                                     \
        for (int j = 0; j < 3; ++j) {                                         \
          iA += ((inc >> (10 * j)) & 0x3ffull) << (16 * j);                   \
          iB += ((inc >> (10 * (j + 3))) & 0x3ffull) << (16 * j);             \
        }                                                                     \
        sW[(K) & 1][wid][0] = iA; sW[(K) & 1][wid][1] = iB;                   \
      }                                                                       \
      __syncthreads();  /* the only barrier of the leg */                     \
      unsigned long long totA = 0ull, totB = 0ull;                            \
      unsigned long long preWA = 0ull, preWB = 0ull;                          \
      _Pragma("unroll")                                                       \
      for (int w = 0; w < NWAVE; ++w) {  /* fields <= 4096 < 65536 */         \
        const unsigned long long vA = sW[(K) & 1][w][0];                      \
        const unsigned long long vB = sW[(K) & 1][w][1];                      \
        totA += vA; totB += vB;                                               \
        preWA += (w < wid) ? vA : 0ull;                                       \
        preWB += (w < wid) ? vB : 0ull;                                       \
      }                                                                       \
      unsigned racc = 0;                                                      \
      _Pragma("unroll")                                                       \
      for (int j = 0; j < NR; ++j) {                                          \
        const int sh = 16 * ((j < 3) ? j : (j - 3));                          \
        const unsigned wpre =                                                 \
            (unsigned)((((j < 3) ? preWA : preWB) >> sh) & 0xffffull);        \
        const unsigned tot =                                                  \
            (unsigned)((((j < 3) ? totA : totB) >> sh) & 0xffffull);          \
        unsigned r = base + racc + wpre +                                     \
                     (unsigned)((exc >> (10 * j)) & 0x3ffull);                \
        const int g = (K) * WIN + j * (TBLK * 4) + tid * 4;                   \
        unsigned m = mbits[j];                                                \
        while (m) {  /* sparse walk: only set bits (mean 0.1/round) */        \
          const int e = (int)__builtin_ctz(m);                                \
          m &= m - 1u;                                                        \
          if (r < MAXS) ob[(int)r] = g + e;                                   \
          ++r;                                                                \
        }                                                                     \
        racc += tot;                                                          \
      }                                                                       \
      base += racc;  /* block-uniform */                                      \
    } while (0)

  // ---- issue the whole window's 18 loads immediately (full MLP) ----
  #pragma unroll
  for (int j = 0; j < NR; ++j) LOADR(0, j);
  PROCESS(0);

  // ---- residual windows (exactness path; P ~ 3e-3 grid-wide) ----
  for (int k = 1; k < nWin && base < MAXS; ++k) {
    #pragma unroll
    for (int j = 0; j < NR; ++j) LOADR(k, j);
    PROCESS(k);
  }
  #undef PROCESS
  #undef LOADR

  // tail: unfilled slots get -1 (zero stores when base >= MAXS)
  for (int i2 = (int)base + tid; i2 < MAXS; i2 += TBLK) ob[i2] = -1;
}

extern "C" void kernel_launch(void* const* d_in, const int* in_sizes, int n_in,
                              void* d_out, int out_size, void* d_ws, size_t ws_size,
                              hipStream_t stream) {
  const float* pcs = (const float*)d_in[0];
  int* out = (int*)d_out;
  const int B = out_size / (8 * MAXS);   // 16
  const int N = in_sizes[0] / (3 * B);   // 200000
  octant_ctz_kernel<<<B * 8, TBLK, 0, stream>>>(pcs, out, N);
}